// Round 5
// baseline (85.494 us; speedup 1.0000x reference)
//
#include <hip/hip_runtime.h>

// SSKernelNPLR, 3-kernel pipeline. H=256, N=32 (M=64 conj-extended), R=1, L=8192.
// K1 (grid 512, 2 blk/CU): block (h,half): A2 contour q_k on 2048 of the 8192nd
//     roots of unity + A3 partial S_m -> Sws.  (dA^T = diag(d) - u p^T; power
//     via spectral contour sum; diagonal part exact as d^L.)
// K2 (grid 512, 2 blk/CU): combine S, z=-1 node, C~ = C - (dA^L)^T C, v-vectors;
//     Cauchy at z_j = 2i tan(pi j/L) + Woodbury + (1+iT) for 2048 nodes;
//     X[j] staged in d_out; X[4096] (Nyquist) -> nyq ws.
// K3 (grid 256): load X, real-irfft packing, 6-stage radix-4 Stockham inverse
//     FFT (4096) in LDS, write k.

#define HH 256
#define NN 32
#define MF 4096

typedef float2 c32;

__device__ __forceinline__ c32 cmul(c32 a, c32 b){ return make_float2(a.x*b.x - a.y*b.y, a.x*b.y + a.y*b.x); }
__device__ __forceinline__ c32 cadd(c32 a, c32 b){ return make_float2(a.x+b.x, a.y+b.y); }
__device__ __forceinline__ c32 csub(c32 a, c32 b){ return make_float2(a.x-b.x, a.y-b.y); }
__device__ __forceinline__ c32 cconjf(c32 a){ return make_float2(a.x, -a.y); }
__device__ __forceinline__ float frcp(float x){ return __builtin_amdgcn_rcpf(x); }

// ---------------- K1: contour halves ----------------
__global__ __launch_bounds__(1024, 8)
void ssk_contour(const float* __restrict__ log_dt, const float* __restrict__ invwr,
                 const float* __restrict__ wim, const float* __restrict__ Pin,
                 const float* __restrict__ Cin, c32* __restrict__ Sws)
{
  __shared__ __align__(16) float4 qz[2048];     // (zx,zy,qx,qy) per node
  __shared__ __align__(16) float4 dpc_s[32];    // (d.x,d.y,pc.x,pc.y)
  __shared__ c32 pu_s[32];
  __shared__ c32 sPart[32*32];

  const int bid = blockIdx.x;
  const int h = bid >> 1;
  const int base = (bid & 1) << 11;             // 0 or 2048
  const int tid = threadIdx.x;

  if (tid < 64) {   // per-head algebra; m = tid, conj half for m>=32
    const int n = tid & 31;
    const bool cj = tid >= 32;
    const float dt = expf(log_dt[h]);
    float wr = -expf(invwr[h*NN + n]);
    float wi = wim[h*NN + n];
    if (cj) wi = -wi;
    const float tdt = 2.0f / dt;
    float dr = tdt - wr, di = -wi;
    float invd = 1.0f / (dr*dr + di*di);
    c32 D = make_float2(dr*invd, -di*invd);     // 1/(2/dt - w)
    c32 E = make_float2(tdt + wr, wi);          // 2/dt + w
    c32 Pf = make_float2(Pin[(h*NN+n)*2], Pin[(h*NN+n)*2+1]);
    if (cj) Pf.y = -Pf.y;
    c32 Cf = make_float2(Cin[(h*NN+n)*2], Cin[(h*NN+n)*2+1]);
    if (cj) Cf.y = -Cf.y;
    float rm = (Pf.x*Pf.x + Pf.y*Pf.y) * D.x;
    #pragma unroll
    for (int off = 32; off >= 1; off >>= 1) rm += __shfl_xor(rm, off, 64);
    rm += 1.0f;
    c32 Rc = cmul(cconjf(Pf), D);
    float invrm = 1.0f / rm;
    Rc.x *= invrm; Rc.y *= invrm;
    c32 RP = cmul(Rc, Pf);
    #pragma unroll
    for (int off = 32; off >= 1; off >>= 1) {
      RP.x += __shfl_xor(RP.x, off, 64);
      RP.y += __shfl_xor(RP.y, off, 64);
    }
    c32 Q2 = cconjf(Pf);
    c32 s  = csub(cmul(Rc, E), cmul(RP, Q2));
    c32 u  = cadd(Q2, s);                       // dA = diag(dd) - pp u^T
    c32 dd = cmul(D, E);
    c32 pp = cmul(D, Pf);
    c32 pc = cmul(pp, Cf);
    c32 pu = cmul(pp, u);
    if (tid < 32) {
      dpc_s[tid] = make_float4(dd.x, dd.y, pc.x, pc.y);
      pu_s[tid]  = pu;
    }
  }
  __syncthreads();

  // A2: q_k at z_k = e^{2pi i k/8192}, nodes k = base + tid + 1024q
  {
    float zx2[2], zy2[2];
    c32 a2[2], b2[2];
    #pragma unroll
    for (int q = 0; q < 2; q++) {
      int k = base + tid + (q << 10);
      float rev = (float)k * (1.0f/8192.0f);
      zx2[q] = __builtin_amdgcn_cosf(rev);
      zy2[q] = __builtin_amdgcn_sinf(rev);
      a2[q] = make_float2(0,0); b2[q] = make_float2(0,0);
    }
    #pragma unroll 2
    for (int m = 0; m < 32; m++) {
      float4 dpc = dpc_s[m];
      c32 pu = pu_s[m];
      #pragma unroll
      for (int q = 0; q < 2; q++) {
        float dxx = zx2[q] - dpc.x;
        float dy1 = zy2[q] - dpc.y;
        float dy2 = zy2[q] + dpc.y;
        float xx  = dxx*dxx;
        float n1  = fmaf(dy1, dy1, xx);
        float n2  = fmaf(dy2, dy2, xx);
        float ip  = frcp(n1*n2);
        float i1  = n2*ip, i2 = n1*ip;
        float glx = dxx*i1, gly = -dy1*i1;      // 1/(z - d)
        float ghx = dxx*i2, ghy = -dy2*i2;      // 1/(z - conj d)
        float sxg = glx+ghx, dxg = glx-ghx, syg = gly+ghy, dyg = gly-ghy;
        a2[q].x = fmaf(dpc.z, sxg, fmaf(-dpc.w, dyg, a2[q].x));
        a2[q].y = fmaf(dpc.z, syg, fmaf( dpc.w, dxg, a2[q].y));
        b2[q].x = fmaf(pu.x, sxg, fmaf(-pu.y, dyg, b2[q].x));
        b2[q].y = fmaf(pu.x, syg, fmaf( pu.y, dxg, b2[q].y));
      }
    }
    #pragma unroll
    for (int q = 0; q < 2; q++) {
      int kl = tid + (q << 10);
      float denx = 1.0f + b2[q].x, deny = b2[q].y;
      float idn = frcp(fmaf(denx, denx, deny*deny));
      float tx = (a2[q].x*denx + a2[q].y*deny)*idn;
      float ty = (a2[q].y*denx - a2[q].x*deny)*idn;
      float qx = zx2[q]*tx - zy2[q]*ty;         // q = z a/(1+b)
      float qy = zx2[q]*ty + zy2[q]*tx;
      if ((base + kl) == 0) { qx *= 0.5f; qy *= 0.5f; }  // self-conj node z=1
      qz[kl] = make_float4(zx2[q], zy2[q], qx, qy);
    }
  }
  __syncthreads();

  // A3: S_m partial = sum_k (q_k g_m + conj(q_k g_m'));  32 chunks x 64 nodes
  {
    const int m = tid & 31;
    const int chunk = tid >> 5;
    const int stag = (chunk & 3) << 1;          // bank-stagger broadcast reads
    float4 da = dpc_s[m];
    c32 s = make_float2(0,0);
    #pragma unroll 2
    for (int kk = 0; kk < 64; kk++) {
      float4 zq = qz[(chunk << 6) + ((kk + stag) & 63)];
      float dxx = zq.x - da.x, dy1 = zq.y - da.y, dy2 = zq.y + da.y;
      float xx = dxx*dxx;
      float n1 = fmaf(dy1,dy1,xx), n2 = fmaf(dy2,dy2,xx);
      float ip = frcp(n1*n2);
      float i1 = n2*ip, i2 = n1*ip;
      float glx = dxx*i1, gly = -dy1*i1;
      float ghx = dxx*i2, ghy = -dy2*i2;
      float sxg = glx+ghx, syg = gly+ghy, dyg = gly-ghy, dxg = glx-ghx;
      s.x = fmaf(zq.z, sxg, fmaf(-zq.w, syg, s.x));
      s.y = fmaf(zq.z, dyg, fmaf( zq.w, dxg, s.y));
    }
    sPart[(chunk << 5) + m] = s;
  }
  __syncthreads();

  if (tid < 32) {
    c32 S = make_float2(0,0);
    #pragma unroll 8
    for (int c = 0; c < 32; c++) {
      c32 v = sPart[(c << 5) + tid];
      S.x += v.x; S.y += v.y;
    }
    Sws[(bid << 5) + tid] = S;    // layout: [h][half][m]
  }
}

// ---------------- K2: combine + Cauchy/Woodbury ----------------
__global__ __launch_bounds__(1024, 8)
void ssk_cauchy(const float* __restrict__ log_dt, const float* __restrict__ invwr,
                const float* __restrict__ wim, const float* __restrict__ Pin,
                const float* __restrict__ Bin, const float* __restrict__ Cin,
                const c32* __restrict__ Sws, float* __restrict__ nyq,
                c32* __restrict__ Xout)
{
  __shared__ c32 wdt_s[NN];
  __shared__ c32 vs[4][NN];
  const int bid = blockIdx.x;
  const int h = bid >> 1;
  const int base = (bid & 1) << 11;
  const int tid = threadIdx.x;

  if (tid < 64) {
    const int n = tid & 31;
    const bool cj = tid >= 32;
    const float dt = expf(log_dt[h]);
    float wr = -expf(invwr[h*NN + n]);
    float wi = wim[h*NN + n];
    if (cj) wi = -wi;
    const float tdt = 2.0f / dt;
    float dr = tdt - wr, di = -wi;
    float invd = 1.0f / (dr*dr + di*di);
    c32 D = make_float2(dr*invd, -di*invd);
    c32 E = make_float2(tdt + wr, wi);
    c32 Pf = make_float2(Pin[(h*NN+n)*2], Pin[(h*NN+n)*2+1]);
    if (cj) Pf.y = -Pf.y;
    c32 Cf = make_float2(Cin[(h*NN+n)*2], Cin[(h*NN+n)*2+1]);
    if (cj) Cf.y = -Cf.y;
    float rm = (Pf.x*Pf.x + Pf.y*Pf.y) * D.x;
    #pragma unroll
    for (int off = 32; off >= 1; off >>= 1) rm += __shfl_xor(rm, off, 64);
    rm += 1.0f;
    c32 Rc = cmul(cconjf(Pf), D);
    float invrm = 1.0f / rm;
    Rc.x *= invrm; Rc.y *= invrm;
    c32 RP = cmul(Rc, Pf);
    #pragma unroll
    for (int off = 32; off >= 1; off >>= 1) {
      RP.x += __shfl_xor(RP.x, off, 64);
      RP.y += __shfl_xor(RP.y, off, 64);
    }
    c32 Q2 = cconjf(Pf);
    c32 s  = csub(cmul(Rc, E), cmul(RP, Q2));
    c32 u  = cadd(Q2, s);
    c32 dd = cmul(D, E);
    c32 pp = cmul(D, Pf);
    c32 pc = cmul(pp, Cf);
    c32 pu = cmul(pp, u);

    // z = -1 node: g = conj(-1-d)/|.|^2 ; a,b real (conj-pair fold)
    float dxxn = -1.0f - dd.x;
    float nn1 = fmaf(dxxn, dxxn, dd.y*dd.y);
    float ii = frcp(nn1);
    float glxn = dxxn*ii, glyn = dd.y*ii;
    float aterm = 2.0f*(pc.x*glxn - pc.y*glyn);
    float bterm = 2.0f*(pu.x*glxn - pu.y*glyn);
    #pragma unroll
    for (int off = 16; off >= 1; off >>= 1) {
      aterm += __shfl_xor(aterm, off, 64);
      bterm += __shfl_xor(bterm, off, 64);
    }

    if (tid < 32) {
      const int m = tid;
      // exact diagonal part d^8192
      c32 dL = dd;
      #pragma unroll
      for (int i2 = 0; i2 < 13; i2++) dL = cmul(dL, dL);
      // total S: both halves + z=-1 node (q real, half weight)
      c32 S = Sws[(h << 6) + m];
      c32 S1 = Sws[(h << 6) + 32 + m];
      S.x += S1.x; S.y += S1.y;
      float qn = -aterm * frcp(1.0f + bterm) * 0.5f;
      S.x += qn * 2.0f * glxn;
      S.y += qn * 2.0f * glyn;
      // C~ = C - (C dL - u S / 8192)
      c32 y = cmul(Cf, dL);
      c32 uS = cmul(u, S);
      y.x -= uS.x * (1.0f/8192.0f);
      y.y -= uS.y * (1.0f/8192.0f);
      c32 Ct = csub(Cf, y);
      // stage-B vectors
      c32 Bc = make_float2(Bin[(h*NN+m)*2], Bin[(h*NN+m)*2+1]);
      c32 Qc = cconjf(Pf);    // lane<32: Pf unconjugated
      c32 v00 = cmul(Bc, Ct), v01 = cmul(Bc, Qc), v10 = cmul(Pf, Ct), v11 = cmul(Pf, Qc);
      vs[0][m] = make_float2(v00.x*dt, v00.y*dt);
      vs[1][m] = make_float2(v01.x*dt, v01.y*dt);
      vs[2][m] = make_float2(v10.x*dt, v10.y*dt);
      vs[3][m] = make_float2(v11.x*dt, v11.y*dt);
      wdt_s[m] = make_float2(wr*dt, wi*dt);
      // Nyquist X[4096] = sum Re(v00*dt)
      float s00 = v00.x * dt;
      #pragma unroll
      for (int off = 16; off >= 1; off >>= 1) s00 += __shfl_xor(s00, off, 64);
      if (m == 0) nyq[h] = s00;
    }
  }
  __syncthreads();

  // Cauchy at z_j = 2i tan(pi j/L), j = base + tid + 1024q
  {
    float Tq[2], t2[2];
    c32 a00[2], a01[2], a10[2], a11[2];
    #pragma unroll
    for (int q = 0; q < 2; q++) {
      int j = base + tid + (q << 10);
      float rev = (float)j * (1.0f/16384.0f);
      float sn = __builtin_amdgcn_sinf(rev);
      float cs = __builtin_amdgcn_cosf(rev);
      float T = sn * frcp(cs);
      Tq[q] = T; t2[q] = 2.0f*T;
      a00[q] = make_float2(0,0); a01[q] = make_float2(0,0);
      a10[q] = make_float2(0,0); a11[q] = make_float2(0,0);
    }
    for (int n = 0; n < NN; n++) {
      c32 w = wdt_s[n];
      float nr  = -w.x;
      float nr2 = nr*nr;
      c32 v0 = vs[0][n], v1 = vs[1][n], v2 = vs[2][n], v3 = vs[3][n];
      #pragma unroll
      for (int q = 0; q < 2; q++) {
        float d1i = t2[q] - w.y;
        float d2i = t2[q] + w.y;
        float n1 = fmaf(d1i, d1i, nr2);
        float n2 = fmaf(d2i, d2i, nr2);
        float ip = frcp(n1*n2);
        float inv1 = n2*ip, inv2 = n1*ip;
        float c1x = nr*inv1, c1y = -d1i*inv1;
        float c2x = nr*inv2, c2y = -d2i*inv2;
        float sx = c1x + c2x, dxx = c1x - c2x;
        float sy = c1y + c2y, dyy = c1y - c2y;
        a00[q].x = fmaf(v0.x, sx, fmaf(-v0.y, dyy, a00[q].x));
        a00[q].y = fmaf(v0.x, sy, fmaf( v0.y, dxx, a00[q].y));
        a01[q].x = fmaf(v1.x, sx, fmaf(-v1.y, dyy, a01[q].x));
        a01[q].y = fmaf(v1.x, sy, fmaf( v1.y, dxx, a01[q].y));
        a10[q].x = fmaf(v2.x, sx, fmaf(-v2.y, dyy, a10[q].x));
        a10[q].y = fmaf(v2.x, sy, fmaf( v2.y, dxx, a10[q].y));
        a11[q].x = fmaf(v3.x, sx, fmaf(-v3.y, dyy, a11[q].x));
        a11[q].y = fmaf(v3.x, sy, fmaf( v3.y, dxx, a11[q].y));
      }
    }
    #pragma unroll
    for (int q = 0; q < 2; q++) {
      int j = base + tid + (q << 10);
      c32 den = make_float2(1.0f + a11[q].x, a11[q].y);
      float idn = 1.0f / (den.x*den.x + den.y*den.y);
      c32 invden = make_float2(den.x*idn, -den.y*idn);
      c32 kf = csub(a00[q], cmul(cmul(a01[q], a10[q]), invden));
      float T = Tq[q];
      Xout[h*MF + j] = make_float2(kf.x - T*kf.y, kf.y + T*kf.x);  // *(1+iT)
    }
  }
}

// ---------------- K3: pack + radix-4 inverse FFT ----------------
__global__ __launch_bounds__(1024)
void ssk_fft(const float* __restrict__ nyq, c32* __restrict__ io)
{
  __shared__ __align__(16) c32 Xs[4098];
  __shared__ __align__(16) c32 Zs[4096];
  const int h = blockIdx.x;
  const int tid = threadIdx.x;

  {
    float4* Xs4 = (float4*)Xs;
    const float4* io4 = (const float4*)(io + (size_t)h*MF);
    Xs4[tid] = io4[tid];
    Xs4[tid + 1024] = io4[tid + 1024];
    if (tid == 0) Xs[MF] = make_float2(nyq[h], 0.0f);
  }
  __syncthreads();

  // real-irfft packing: Z[k] = (E[k] + i*O[k]) / MF
  const float invM = 1.0f / (float)MF;
  #pragma unroll
  for (int qq = 0; qq < 4; qq++) {
    int k = tid + (qq << 10);
    c32 Xk = Xs[k];
    c32 Xm = Xs[MF - k];
    float Ex = 0.5f*(Xk.x + Xm.x), Ey = 0.5f*(Xk.y - Xm.y);
    float Ox = 0.5f*(Xk.x - Xm.x), Oy = 0.5f*(Xk.y + Xm.y);
    float rev = (float)k * (1.0f/8192.0f);
    float cs = __builtin_amdgcn_cosf(rev);
    float sn = __builtin_amdgcn_sinf(rev);
    float Orx = Ox*cs - Oy*sn;
    float Ory = Ox*sn + Oy*cs;
    Zs[k] = make_float2((Ex - Ory)*invM, (Ey + Orx)*invM);
  }
  __syncthreads();

  // 6-stage radix-4 Stockham inverse FFT (twiddle sign +, +i butterfly)
  c32* srcf = Zs;
  c32* dstf = Xs;
  int sstride = 1;
  #pragma unroll
  for (int st = 0; st < 6; st++) {
    int jm = tid & ~(sstride - 1);        // p * sstride
    float rev = (float)jm * (1.0f/4096.0f);
    float sn = __builtin_amdgcn_sinf(rev);
    float cs = __builtin_amdgcn_cosf(rev);
    c32 w1 = make_float2(cs, sn);
    c32 w2 = cmul(w1, w1);
    c32 w3 = cmul(w2, w1);
    c32 a = srcf[tid];
    c32 b = srcf[tid + 1024];
    c32 c = srcf[tid + 2048];
    c32 d = srcf[tid + 3072];
    c32 apc = cadd(a, c), amc = csub(a, c);
    c32 bpd = cadd(b, d), bmd = csub(b, d);
    int wb = tid + 3*jm;
    dstf[wb] = cadd(apc, bpd);
    dstf[wb + sstride]     = cmul(w1, make_float2(amc.x - bmd.y, amc.y + bmd.x)); // *( +i bmd )
    dstf[wb + 2*sstride]   = cmul(w2, csub(apc, bpd));
    dstf[wb + 3*sstride]   = cmul(w3, make_float2(amc.x + bmd.y, amc.y - bmd.x)); // *( -i bmd )
    __syncthreads();
    c32* t = srcf; srcf = dstf; dstf = t;
    sstride <<= 2;
  }

  // even stage count -> result back in Zs (= srcf); z[m] = (x[2m], x[2m+1])
  {
    float4* o4 = (float4*)(io + (size_t)h*MF);
    const float4* s4 = (const float4*)srcf;
    o4[tid] = s4[tid];
    o4[tid + 1024] = s4[tid + 1024];
  }
}

extern "C" void kernel_launch(void* const* d_in, const int* in_sizes, int n_in,
                              void* d_out, int out_size, void* d_ws, size_t ws_size,
                              hipStream_t stream) {
  const float* log_dt = (const float*)d_in[0];
  const float* invwr  = (const float*)d_in[1];
  const float* wimag  = (const float*)d_in[2];
  const float* P      = (const float*)d_in[3];
  const float* B      = (const float*)d_in[4];
  const float* C      = (const float*)d_in[5];
  c32*   Sws = (c32*)d_ws;                          // 512*32 c32 = 128 KB
  float* nyq = (float*)((char*)d_ws + 131072);      // 256 floats
  c32*   out = (c32*)d_out;                         // (H,8192) fp32 = (H,4096) c32
  (void)in_sizes; (void)n_in; (void)out_size; (void)ws_size;

  ssk_contour<<<2*HH, 1024, 0, stream>>>(log_dt, invwr, wimag, P, C, Sws);
  ssk_cauchy <<<2*HH, 1024, 0, stream>>>(log_dt, invwr, wimag, P, B, C, Sws, nyq, out);
  ssk_fft    <<<HH,   1024, 0, stream>>>(nyq, out);
}

// Round 6
// 81.912 us; speedup vs baseline: 1.0437x; 1.0437x over previous
//
#include <hip/hip_runtime.h>

// SSKernelNPLR, 2-kernel pipeline. H=256, N=32 (M=64 conj-extended), R=1, L=8192.
// K1 (grid 256, 1024 thr): A1 per-head algebra (dA^T = diag(d) - u p^T);
//    A2: contour scalars q_k = z_k a_k/(1+b_k) at 4096 of the 8192nd roots of
//    unity (4 nodes/thread); A3: S_m = sum_k [q_k g_lo + conj(q_k g_hi)]
//    (128 node-evals/thread); combine: + z=-1 node, C~ = C - (C d^L - u S/8192),
//    v-vectors -> 3xfloat4/state table in ws + Nyquist scalar.
// K23 (grid 256, 1024 thr): Cauchy at z_j = 2i tan(pi j/L) (4 nodes/thread) +
//    rank-1 Woodbury + (1+iT) -> X in LDS; real-irfft packing; 6-stage radix-4
//    Stockham inverse FFT (4096) in LDS -> out.

#define HH 256
#define NN 32
#define MF 4096

typedef float2 c32;

__device__ __forceinline__ c32 cmul(c32 a, c32 b){ return make_float2(a.x*b.x - a.y*b.y, a.x*b.y + a.y*b.x); }
__device__ __forceinline__ c32 cadd(c32 a, c32 b){ return make_float2(a.x+b.x, a.y+b.y); }
__device__ __forceinline__ c32 csub(c32 a, c32 b){ return make_float2(a.x-b.x, a.y-b.y); }
__device__ __forceinline__ c32 cconjf(c32 a){ return make_float2(a.x, -a.y); }
__device__ __forceinline__ float frcp(float x){ return __builtin_amdgcn_rcpf(x); }

// ---------------- K1: contour -> C~ -> B-stage tables ----------------
__global__ __launch_bounds__(1024, 4)
void ssk_A(const float* __restrict__ log_dt, const float* __restrict__ invwr,
           const float* __restrict__ wim, const float* __restrict__ Pin,
           const float* __restrict__ Bin, const float* __restrict__ Cin,
           float4* __restrict__ tblB, float* __restrict__ nyq)
{
  __shared__ __align__(16) float4 qz[4096];     // (zx,zy,qx,qy) per node, 64KB
  __shared__ __align__(16) c32 sPart[32*32];    // 8KB partials
  __shared__ __align__(16) float4 ta_s[32];     // (d.x, d.y, pc.x, pc.y)
  __shared__ __align__(16) float4 tb_s[32];     // (pu.x, pu.y, glm1.x, glm1.y)
  __shared__ c32 u_s[32], C_s[32], dL_s[32];
  __shared__ float abn_s[2];                    // aterm, bterm at z=-1
  const int h = blockIdx.x;
  const int tid = threadIdx.x;

  // ---- A1: per-head algebra (wave 0; m = tid, conj half for m>=32) ----
  if (tid < 64) {
    const int n = tid & 31;
    const bool cj = tid >= 32;
    const float dt = expf(log_dt[h]);
    float wr = -expf(invwr[h*NN + n]);
    float wi = wim[h*NN + n];
    if (cj) wi = -wi;
    const float tdt = 2.0f / dt;
    float dr = tdt - wr, di = -wi;
    float invd = 1.0f / (dr*dr + di*di);
    c32 D = make_float2(dr*invd, -di*invd);     // 1/(2/dt - w)
    c32 E = make_float2(tdt + wr, wi);          // 2/dt + w
    c32 Pf = make_float2(Pin[(h*NN+n)*2], Pin[(h*NN+n)*2+1]);
    if (cj) Pf.y = -Pf.y;
    c32 Cf = make_float2(Cin[(h*NN+n)*2], Cin[(h*NN+n)*2+1]);
    if (cj) Cf.y = -Cf.y;
    float rm = (Pf.x*Pf.x + Pf.y*Pf.y) * D.x;   // Rm = 1 + sum |Pf|^2 Re(D)
    #pragma unroll
    for (int off = 32; off >= 1; off >>= 1) rm += __shfl_xor(rm, off, 64);
    rm += 1.0f;
    c32 Rc = cmul(cconjf(Pf), D);
    float invrm = 1.0f / rm;
    Rc.x *= invrm; Rc.y *= invrm;
    c32 RP = cmul(Rc, Pf);
    #pragma unroll
    for (int off = 32; off >= 1; off >>= 1) {
      RP.x += __shfl_xor(RP.x, off, 64);
      RP.y += __shfl_xor(RP.y, off, 64);
    }
    c32 Q2 = cconjf(Pf);
    c32 s  = csub(cmul(Rc, E), cmul(RP, Q2));
    c32 u  = cadd(Q2, s);                       // dA = diag(dd) - pp u^T
    c32 dd = cmul(D, E);
    c32 pp = cmul(D, Pf);
    c32 pc = cmul(pp, Cf);
    c32 pu = cmul(pp, u);

    // z = -1 node pieces: g = conj(-1-d)/|.|^2 ; a,b real via conj-pair fold
    float dxxn = -1.0f - dd.x;
    float nn1 = fmaf(dxxn, dxxn, dd.y*dd.y);
    float ii = frcp(nn1);
    float glxn = dxxn*ii, glyn = dd.y*ii;
    float aterm = 2.0f*(pc.x*glxn - pc.y*glyn);
    float bterm = 2.0f*(pu.x*glxn - pu.y*glyn);
    #pragma unroll
    for (int off = 16; off >= 1; off >>= 1) {
      aterm += __shfl_xor(aterm, off, 64);
      bterm += __shfl_xor(bterm, off, 64);
    }
    if (tid < 32) {
      ta_s[tid] = make_float4(dd.x, dd.y, pc.x, pc.y);
      tb_s[tid] = make_float4(pu.x, pu.y, glxn, glyn);
      u_s[tid] = u; C_s[tid] = Cf;
      c32 t = dd;                               // d^8192 by 13 squarings
      #pragma unroll
      for (int i2 = 0; i2 < 13; i2++) t = cmul(t, t);
      dL_s[tid] = t;
    }
    if (tid == 0) { abn_s[0] = aterm; abn_s[1] = bterm; }
  }
  __syncthreads();

  // ---- A2: q_k at z_k = e^{2pi i k/8192}, k = tid + 1024q, q<4 ----
  {
    float zx4[4], zy4[4];
    c32 a4[4], b4[4];
    #pragma unroll
    for (int q = 0; q < 4; q++) {
      int k = tid + (q << 10);
      float rev = (float)k * (1.0f/8192.0f);
      zx4[q] = __builtin_amdgcn_cosf(rev);
      zy4[q] = __builtin_amdgcn_sinf(rev);
      a4[q] = make_float2(0,0); b4[q] = make_float2(0,0);
    }
    #pragma unroll 4
    for (int m = 0; m < 32; m++) {
      float4 ta = ta_s[m];    // d.x, d.y, pc.x, pc.y
      float4 tb = tb_s[m];    // pu.x, pu.y
      #pragma unroll
      for (int q = 0; q < 4; q++) {
        float dxx = zx4[q] - ta.x;
        float dy1 = zy4[q] - ta.y;
        float dy2 = zy4[q] + ta.y;
        float xx  = dxx*dxx;
        float n1  = fmaf(dy1, dy1, xx);
        float n2  = fmaf(dy2, dy2, xx);
        float ip  = frcp(n1*n2);
        float i1  = n2*ip, i2 = n1*ip;
        float glx = dxx*i1, gly = -dy1*i1;      // 1/(z - d)
        float ghx = dxx*i2, ghy = -dy2*i2;      // 1/(z - conj d)
        float sxg = glx+ghx, dxg = glx-ghx, syg = gly+ghy, dyg = gly-ghy;
        a4[q].x = fmaf(ta.z, sxg, fmaf(-ta.w, dyg, a4[q].x));
        a4[q].y = fmaf(ta.z, syg, fmaf( ta.w, dxg, a4[q].y));
        b4[q].x = fmaf(tb.x, sxg, fmaf(-tb.y, dyg, b4[q].x));
        b4[q].y = fmaf(tb.x, syg, fmaf( tb.y, dxg, b4[q].y));
      }
    }
    #pragma unroll
    for (int q = 0; q < 4; q++) {
      float denx = 1.0f + b4[q].x, deny = b4[q].y;
      float idn = frcp(fmaf(denx, denx, deny*deny));
      float tx = (a4[q].x*denx + a4[q].y*deny)*idn;
      float ty = (a4[q].y*denx - a4[q].x*deny)*idn;
      float qx = zx4[q]*tx - zy4[q]*ty;         // q = z a/(1+b)
      float qy = zx4[q]*ty + zy4[q]*tx;
      if (tid == 0 && q == 0) { qx *= 0.5f; qy *= 0.5f; }   // self-conj z=1
      qz[tid + (q << 10)] = make_float4(zx4[q], zy4[q], qx, qy);
    }
  }
  __syncthreads();

  // ---- A3: S_m partials; 32 chunks x 128 nodes, m = tid&31 ----
  {
    const int m = tid & 31;
    const int chunk = tid >> 5;
    float4 ta = ta_s[m];
    c32 s = make_float2(0,0);
    #pragma unroll 2
    for (int kk = 0; kk < 128; kk++) {
      float4 zq = qz[(chunk << 7) + kk];
      float dxx = zq.x - ta.x, dy1 = zq.y - ta.y, dy2 = zq.y + ta.y;
      float xx = dxx*dxx;
      float n1 = fmaf(dy1,dy1,xx), n2 = fmaf(dy2,dy2,xx);
      float ip = frcp(n1*n2);
      float i1 = n2*ip, i2 = n1*ip;
      float glx = dxx*i1, gly = -dy1*i1;
      float ghx = dxx*i2, ghy = -dy2*i2;
      float sxg = glx+ghx, syg = gly+ghy, dyg = gly-ghy, dxg = glx-ghx;
      s.x = fmaf(zq.z, sxg, fmaf(-zq.w, syg, s.x));
      s.y = fmaf(zq.z, dyg, fmaf( zq.w, dxg, s.y));
    }
    sPart[(chunk << 5) + m] = s;
  }
  __syncthreads();

  // ---- combine: S total, z=-1 node, C~, B-stage tables (lanes 0..31) ----
  if (tid < 32) {
    const int m = tid;
    c32 S = make_float2(0,0);
    #pragma unroll 8
    for (int c = 0; c < 32; c++) {
      c32 v = sPart[(c << 5) + m];
      S.x += v.x; S.y += v.y;
    }
    float4 tb = tb_s[m];
    float qn = -abn_s[0] * frcp(1.0f + abn_s[1]) * 0.5f;
    S.x += qn * 2.0f * tb.z;
    S.y += qn * 2.0f * tb.w;
    c32 y = cmul(C_s[m], dL_s[m]);              // exact diagonal part
    c32 uS = cmul(u_s[m], S);
    y.x -= uS.x * (1.0f/8192.0f);
    y.y -= uS.y * (1.0f/8192.0f);
    c32 Ct = csub(C_s[m], y);                   // C~ = C - (dA^L)^T C

    const float dt = expf(log_dt[h]);
    float wr = -expf(invwr[h*NN + m]);
    float wi = wim[h*NN + m];
    c32 Bc = make_float2(Bin[(h*NN+m)*2], Bin[(h*NN+m)*2+1]);
    c32 Pc = make_float2(Pin[(h*NN+m)*2], Pin[(h*NN+m)*2+1]);
    c32 Qc = cconjf(Pc);
    c32 v00 = cmul(Bc, Ct), v01 = cmul(Bc, Qc), v10 = cmul(Pc, Ct), v11 = cmul(Pc, Qc);
    v00.x *= dt; v00.y *= dt; v01.x *= dt; v01.y *= dt;
    v10.x *= dt; v10.y *= dt; v11.x *= dt; v11.y *= dt;
    float nr = -wr*dt;
    tblB[h*96 + m]      = make_float4(nr, nr*nr, wi*dt, 0.0f);
    tblB[h*96 + 32 + m] = make_float4(v00.x, v00.y, v01.x, v01.y);
    tblB[h*96 + 64 + m] = make_float4(v10.x, v10.y, v11.x, v11.y);
    // Nyquist X[4096] = sum Re(v00*dt)
    float s00 = v00.x;
    #pragma unroll
    for (int off = 16; off >= 1; off >>= 1) s00 += __shfl_xor(s00, off, 64);
    if (m == 0) nyq[h] = s00;
  }
}

// ---------------- K23: Cauchy + Woodbury + irfft ----------------
__global__ __launch_bounds__(1024, 4)
void ssk_B(const float4* __restrict__ tblB, const float* __restrict__ nyq,
           c32* __restrict__ out)
{
  __shared__ __align__(16) c32 Xs[4098];   // spectrum / FFT ping
  __shared__ __align__(16) c32 Zs[4096];   // packed seq / FFT pong
  __shared__ __align__(16) float4 t1_s[32], t2_s[32], t3_s[32];
  const int h = blockIdx.x;
  const int tid = threadIdx.x;

  if (tid < 32) {
    t1_s[tid] = tblB[h*96 + tid];
    t2_s[tid] = tblB[h*96 + 32 + tid];
    t3_s[tid] = tblB[h*96 + 64 + tid];
  }
  if (tid == 0) Xs[MF] = make_float2(nyq[h], 0.0f);
  __syncthreads();

  // ---- Cauchy at z_j = 2i tan(pi j/L), 4 nodes/thread ----
  {
    float Tq[4], t2[4];
    c32 a00[4], a01[4], a10[4], a11[4];
    #pragma unroll
    for (int q = 0; q < 4; q++) {
      int j = tid + (q << 10);
      float rev = (float)j * (1.0f/16384.0f);
      float sn = __builtin_amdgcn_sinf(rev);
      float cs = __builtin_amdgcn_cosf(rev);
      float T = sn * frcp(cs);
      Tq[q] = T; t2[q] = 2.0f*T;
      a00[q] = make_float2(0,0); a01[q] = make_float2(0,0);
      a10[q] = make_float2(0,0); a11[q] = make_float2(0,0);
    }
    #pragma unroll 2
    for (int n = 0; n < NN; n++) {
      float4 T1 = t1_s[n];   // nr, nr2, wy
      float4 T2 = t2_s[n];   // v00, v01
      float4 T3 = t3_s[n];   // v10, v11
      float nr = T1.x, nr2 = T1.y, wy = T1.z;
      #pragma unroll
      for (int q = 0; q < 4; q++) {
        float d1i = t2[q] - wy;
        float d2i = t2[q] + wy;
        float n1 = fmaf(d1i, d1i, nr2);
        float n2 = fmaf(d2i, d2i, nr2);
        float ip = frcp(n1*n2);
        float inv1 = n2*ip, inv2 = n1*ip;
        float c1x = nr*inv1, c1y = -d1i*inv1;
        float c2x = nr*inv2, c2y = -d2i*inv2;
        float sx = c1x + c2x, dxx = c1x - c2x;
        float sy = c1y + c2y, dyy = c1y - c2y;
        a00[q].x = fmaf(T2.x, sx, fmaf(-T2.y, dyy, a00[q].x));
        a00[q].y = fmaf(T2.x, sy, fmaf( T2.y, dxx, a00[q].y));
        a01[q].x = fmaf(T2.z, sx, fmaf(-T2.w, dyy, a01[q].x));
        a01[q].y = fmaf(T2.z, sy, fmaf( T2.w, dxx, a01[q].y));
        a10[q].x = fmaf(T3.x, sx, fmaf(-T3.y, dyy, a10[q].x));
        a10[q].y = fmaf(T3.x, sy, fmaf( T3.y, dxx, a10[q].y));
        a11[q].x = fmaf(T3.z, sx, fmaf(-T3.w, dyy, a11[q].x));
        a11[q].y = fmaf(T3.z, sy, fmaf( T3.w, dxx, a11[q].y));
      }
    }
    #pragma unroll
    for (int q = 0; q < 4; q++) {
      float denx = 1.0f + a11[q].x, deny = a11[q].y;
      float idn = frcp(fmaf(denx, denx, deny*deny));
      c32 invden = make_float2(denx*idn, -deny*idn);
      c32 kf = csub(a00[q], cmul(cmul(a01[q], a10[q]), invden));
      float T = Tq[q];
      Xs[tid + (q << 10)] = make_float2(kf.x - T*kf.y, kf.y + T*kf.x);  // *(1+iT)
    }
  }
  __syncthreads();

  // ---- real-irfft packing: Z[k] = (E[k] + i*O[k]) / MF ----
  const float invM = 1.0f / (float)MF;
  #pragma unroll
  for (int qq = 0; qq < 4; qq++) {
    int k = tid + (qq << 10);
    c32 Xk = Xs[k];
    c32 Xm = Xs[MF - k];
    float Ex = 0.5f*(Xk.x + Xm.x), Ey = 0.5f*(Xk.y - Xm.y);
    float Ox = 0.5f*(Xk.x - Xm.x), Oy = 0.5f*(Xk.y + Xm.y);
    float rev = (float)k * (1.0f/8192.0f);
    float cs = __builtin_amdgcn_cosf(rev);
    float sn = __builtin_amdgcn_sinf(rev);
    float Orx = Ox*cs - Oy*sn;
    float Ory = Ox*sn + Oy*cs;
    Zs[k] = make_float2((Ex - Ory)*invM, (Ey + Orx)*invM);
  }
  __syncthreads();

  // ---- 6-stage radix-4 Stockham inverse FFT (twiddle sign +) ----
  c32* srcf = Zs;
  c32* dstf = Xs;
  int sstride = 1;
  #pragma unroll
  for (int st = 0; st < 6; st++) {
    int jm = tid & ~(sstride - 1);
    float rev = (float)jm * (1.0f/4096.0f);
    float sn = __builtin_amdgcn_sinf(rev);
    float cs = __builtin_amdgcn_cosf(rev);
    c32 w1 = make_float2(cs, sn);
    c32 w2 = cmul(w1, w1);
    c32 w3 = cmul(w2, w1);
    c32 a = srcf[tid];
    c32 b = srcf[tid + 1024];
    c32 c = srcf[tid + 2048];
    c32 d = srcf[tid + 3072];
    c32 apc = cadd(a, c), amc = csub(a, c);
    c32 bpd = cadd(b, d), bmd = csub(b, d);
    int wb = tid + 3*jm;
    dstf[wb] = cadd(apc, bpd);
    dstf[wb + sstride]   = cmul(w1, make_float2(amc.x - bmd.y, amc.y + bmd.x));
    dstf[wb + 2*sstride] = cmul(w2, csub(apc, bpd));
    dstf[wb + 3*sstride] = cmul(w3, make_float2(amc.x + bmd.y, amc.y - bmd.x));
    __syncthreads();
    c32* t = srcf; srcf = dstf; dstf = t;
    sstride <<= 2;
  }

  // even stage count -> result in Zs (= srcf); z[m] = (x[2m], x[2m+1])
  {
    float4* o4 = (float4*)(out + (size_t)h*MF);
    const float4* s4 = (const float4*)srcf;
    o4[tid] = s4[tid];
    o4[tid + 1024] = s4[tid + 1024];
  }
}

extern "C" void kernel_launch(void* const* d_in, const int* in_sizes, int n_in,
                              void* d_out, int out_size, void* d_ws, size_t ws_size,
                              hipStream_t stream) {
  const float* log_dt = (const float*)d_in[0];
  const float* invwr  = (const float*)d_in[1];
  const float* wimag  = (const float*)d_in[2];
  const float* P      = (const float*)d_in[3];
  const float* B      = (const float*)d_in[4];
  const float* C      = (const float*)d_in[5];
  float4* tblB = (float4*)d_ws;                        // 256*96 float4 = 384 KB
  float*  nyqp = (float*)((char*)d_ws + 256*96*16);    // 256 floats
  c32*    out  = (c32*)d_out;                          // (H,8192) fp32 = (H,4096) c32
  (void)in_sizes; (void)n_in; (void)out_size; (void)ws_size;

  ssk_A<<<HH, 1024, 0, stream>>>(log_dt, invwr, wimag, P, B, C, tblB, nyqp);
  ssk_B<<<HH, 1024, 0, stream>>>(tblB, nyqp, out);
}